// Round 3
// baseline (4824.269 us; speedup 1.0000x reference)
//
#include <hip/hip_runtime.h>
#include <hip/hip_bf16.h>
#include <stdint.h>

#define B_   64
#define T_   1024
#define D_   300
#define H_   512
#define G4H  2048
#define KP   320   // K padded to multiple of 32 for the x-proj GEMM

typedef __attribute__((ext_vector_type(8))) short short8;   // 8 x bf16 (4 VGPRs)
typedef __attribute__((ext_vector_type(4))) float f32x4;
typedef unsigned long long ull;

__device__ __forceinline__ unsigned short f2bf(float v) {
    __hip_bfloat16 h = __float2bfloat16(v);
    return *reinterpret_cast<unsigned short*>(&h);
}
__device__ __forceinline__ float bf2f(unsigned u) {      // low 16 bits = bf16
    return __uint_as_float(u << 16);
}
__device__ __forceinline__ float sigm(float x) { return 1.f / (1.f + __expf(-x)); }
__device__ __forceinline__ float tanhfast(float x) {
    float e = __expf(2.f * x);            // inf-safe: x>>0 -> 1, x<<0 -> -1
    return 1.f - 2.f / (e + 1.f);
}

#define ASYNC16(g, l)                                                        \
    __builtin_amdgcn_global_load_lds(                                        \
        (const __attribute__((address_space(1))) void*)(g),                  \
        (__attribute__((address_space(3))) void*)(l), 16, 0, 0)

// ---------------------------------------------------------------------------
// Kernel 1: essays fp32 [65536][300] -> bf16 [65536][320] (zero-padded K)
// ---------------------------------------------------------------------------
__global__ void cvt_essays(const float* __restrict__ es, unsigned short* __restrict__ Ab) {
    unsigned i = blockIdx.x * 256u + threadIdx.x;       // exactly 65536*320 threads
    unsigned row = i / KP;
    unsigned col = i - row * KP;
    float v = (col < D_) ? es[(size_t)row * D_ + col] : 0.f;
    Ab[i] = f2bf(v);
}

// ---------------------------------------------------------------------------
// Kernel 2: Wx transpose+pad -> bf16 WxT[2048][320]; zero h ping-pong + flags
// ---------------------------------------------------------------------------
__global__ void cvt_misc(const float* __restrict__ Wl, unsigned short* __restrict__ Bt,
                         unsigned short* __restrict__ hbuf, unsigned int* __restrict__ flags) {
    unsigned i = blockIdx.x * 256u + threadIdx.x;       // exactly 2048*320 threads
    {
        unsigned n = i / KP, k = i - n * KP;
        float v = (k < D_) ? Wl[(size_t)k * G4H + n] : 0.f;   // Wx rows 0..299
        Bt[i] = f2bf(v);
    }
    if (i < 2u * 64u * 512u) hbuf[i] = 0;               // both ping-pong buffers
    if (i < 256u) flags[i] = 0u;                        // per-slice seq flags
}

// ---------------------------------------------------------------------------
// Kernel 2b: Wh transpose -> bf16 WhTg[2048][512] (coalesced reads)
// ---------------------------------------------------------------------------
__global__ void cvt_wh(const float* __restrict__ Wl, unsigned short* __restrict__ WhTg) {
    unsigned i = blockIdx.x * 256u + threadIdx.x;       // 2048*512 threads
    unsigned gc = i & 2047u, k = i >> 11;
    WhTg[(size_t)gc * 512 + k] = f2bf(Wl[(size_t)(300 + k) * G4H + gc]);
}

// ---------------------------------------------------------------------------
// Kernel 3: x_proj GEMM  C[65536][2048] = A[65536][320] @ WxT^T + b_lstm (bf16 out)
// ---------------------------------------------------------------------------
__global__ __launch_bounds__(256) void gemm_xp(
    const unsigned short* __restrict__ Ab,   // [65536][320] bf16
    const unsigned short* __restrict__ Bt,   // [2048][320]  bf16 (WxT)
    const float* __restrict__ bias,          // [2048]
    unsigned short* __restrict__ Cb)         // [65536][2048] bf16
{
    __shared__ __align__(16) unsigned short Al[128 * 32];
    __shared__ __align__(16) unsigned short Bl[128 * 32];
    const int tid = threadIdx.x;
    const int w = tid >> 6, lane = tid & 63;
    const int ln = lane & 15, q = lane >> 4;
    const int bx = blockIdx.x;
    const int m0 = (bx >> 4) * 128;          // consecutive blocks share the A tile
    const int n0 = (bx & 15) * 128;
    const int wr = w >> 1, wc = w & 1;

    f32x4 acc[4][4];
#pragma unroll
    for (int i = 0; i < 4; i++)
#pragma unroll
        for (int j = 0; j < 4; j++) acc[i][j] = (f32x4){0.f, 0.f, 0.f, 0.f};

    for (int k0 = 0; k0 < KP; k0 += 32) {
#pragma unroll
        for (int it = 0; it < 2; ++it) {
            int s = it * 4 + w;              // wave-uniform segment id
            int c = s * 64 + lane;           // 16B chunk id, 0..511
            int r = c >> 2;                  // tile row 0..127
            int ko = (c & 3) * 8;            // k offset in elements
            ASYNC16(Ab + (size_t)(m0 + r) * KP + k0 + ko, &Al[s * 512]);
            ASYNC16(Bt + (size_t)(n0 + r) * KP + k0 + ko, &Bl[s * 512]);
        }
        __syncthreads();
        short8 af[4], bf[4];
#pragma unroll
        for (int mt = 0; mt < 4; ++mt)
            af[mt] = *(const short8*)&Al[(wr * 64 + mt * 16 + ln) * 32 + q * 8];
#pragma unroll
        for (int nt = 0; nt < 4; ++nt)
            bf[nt] = *(const short8*)&Bl[(wc * 64 + nt * 16 + ln) * 32 + q * 8];
#pragma unroll
        for (int mt = 0; mt < 4; ++mt)
#pragma unroll
            for (int nt = 0; nt < 4; ++nt)
                acc[mt][nt] = __builtin_amdgcn_mfma_f32_16x16x32_bf16(af[mt], bf[nt], acc[mt][nt], 0, 0, 0);
        __syncthreads();
    }
#pragma unroll
    for (int mt = 0; mt < 4; ++mt) {
#pragma unroll
        for (int nt = 0; nt < 4; ++nt) {
            int col = n0 + wc * 64 + nt * 16 + ln;
            float bb = bias[col];
#pragma unroll
            for (int r = 0; r < 4; ++r) {
                int row = m0 + wr * 64 + mt * 16 + q * 4 + r;   // C/D: col=lane&15, row=quad*4+reg
                Cb[(size_t)row * G4H + col] = f2bf(acc[mt][nt][r] + bb);
            }
        }
    }
}

// ---------------------------------------------------------------------------
// Kernel 4: persistent LSTM recurrence.
// 4 batch groups x 16 j-blocks (32 j each) = 64 blocks, 1/CU, co-resident.
// Barrier: per-slice seq flags (plain agent stores, no RMW); all waves poll
// all 16 flags with one coalesced load + ballot. h exchange agent-scope at L3.
// ---------------------------------------------------------------------------
__global__ __launch_bounds__(256, 1) void lstm_rec(
    const unsigned short* __restrict__ WhTg, // [2048][512] bf16 (pre-transposed Wh)
    const unsigned short* __restrict__ xp,   // [65536][2048] bf16 (x_proj + bias)
    unsigned short* __restrict__ hbuf,       // [2][64][512] bf16 ping-pong
    float* __restrict__ hmean,               // [64][512] fp32
    unsigned int* __restrict__ flags)        // [4 * 64] per-slice seq numbers
{
    __shared__ __align__(16) unsigned short WhT[128 * 520];  // [col][k], pad 520
    __shared__ __align__(16) unsigned short hl[16 * 520];    // [b][k], pad 520
    __shared__ float gbuf[4][16][35];                        // [gate][b][j], pad 35

    const int tid = threadIdx.x;
    const int bid = blockIdx.x;
    const int g     = bid >> 4;         // batch group 0..3
    const int slice = bid & 15;         // j-slice 0..15
    const int j0    = slice * 32;
    const int bg    = g * 16;
    const int wv = tid >> 6, lane = tid & 63, ln = lane & 15, q = lane >> 4;

    // one-time: stage this block's 128 Wh columns (gate*32+j) from WhTg, coalesced
    for (int ch = tid; ch < 128 * 64; ch += 256) {           // 16B chunks
        int c = ch >> 6, off = (ch & 63) * 8;
        int gc = (c >> 5) * 512 + j0 + (c & 31);
        *(uint4*)&WhT[c * 520 + off] = *(const uint4*)&WhTg[(size_t)gc * 512 + off];
    }

    const int b  = tid >> 4;            // local batch row 0..15
    const int jj = tid & 15;            // j pair index; j = 2*jj, 2*jj+1
    float c0 = 0.f, c1 = 0.f, hs0 = 0.f, hs1 = 0.f;

    const unsigned short* xrow = xp + (size_t)(bg + b) * T_ * G4H + j0 + 2 * jj;
    unsigned xc0 = *(const unsigned*)(xrow);
    unsigned xc1 = *(const unsigned*)(xrow + 512);
    unsigned xc2 = *(const unsigned*)(xrow + 1024);
    unsigned xc3 = *(const unsigned*)(xrow + 1536);
    unsigned xn0 = 0, xn1 = 0, xn2 = 0, xn3 = 0;

    ull* const hl8 = (ull*)hl;
    const unsigned int* fl = flags + g * 64 + (lane & 15);

    for (int t = 0; t < T_; ++t) {
        if (t > 0) {
            const unsigned tgt = (unsigned)t;
            while (true) {
                unsigned v = __hip_atomic_load(fl, __ATOMIC_RELAXED, __HIP_MEMORY_SCOPE_AGENT);
                if (__ballot((int)(v >= tgt)) == ~0ull) break;
            }
            xc0 = xn0; xc1 = xn1; xc2 = xn2; xc3 = xn3;
        }
        // prefetch xp(t+1): overlaps the h stage loads under the same drain
        if (t + 1 < T_) {
            const unsigned short* xr = xrow + (size_t)(t + 1) * G4H;
            xn0 = *(const unsigned*)(xr);
            xn1 = *(const unsigned*)(xr + 512);
            xn2 = *(const unsigned*)(xr + 1024);
            xn3 = *(const unsigned*)(xr + 1536);
        }
        // stage h(t) -> LDS via agent-scope 8B loads (16 rows x 512 bf16)
        {
            const ull* hb8 = (const ull*)(hbuf + (size_t)(t & 1) * 32768) + (size_t)bg * 128;
#pragma unroll
            for (int i = 0; i < 8; ++i) {
                int c = tid + (i << 8);                      // 0..2047 8B chunks
                ull v = __hip_atomic_load(hb8 + c, __ATOMIC_RELAXED, __HIP_MEMORY_SCOPE_AGENT);
                hl8[(c >> 7) * 130 + (c & 127)] = v;
            }
        }
        __syncthreads();                                     // sync1 (also covers WhT init at t=0)

        // wave wv = gate wv; 2 N-tiles of 16 cols; K=512
        f32x4 a0 = (f32x4){0.f, 0.f, 0.f, 0.f};
        f32x4 a1 = (f32x4){0.f, 0.f, 0.f, 0.f};
#pragma unroll
        for (int kk = 0; kk < 16; ++kk) {
            short8 av = *(const short8*)&hl[ln * 520 + kk * 32 + q * 8];
            short8 b0 = *(const short8*)&WhT[(wv * 32 + ln) * 520 + kk * 32 + q * 8];
            short8 b1 = *(const short8*)&WhT[(wv * 32 + 16 + ln) * 520 + kk * 32 + q * 8];
            a0 = __builtin_amdgcn_mfma_f32_16x16x32_bf16(av, b0, a0, 0, 0, 0);
            a1 = __builtin_amdgcn_mfma_f32_16x16x32_bf16(av, b1, a1, 0, 0, 0);
        }
#pragma unroll
        for (int r = 0; r < 4; ++r) {
            gbuf[wv][q * 4 + r][ln]      = a0[r];            // C/D: col=lane&15, row=quad*4+reg
            gbuf[wv][q * 4 + r][16 + ln] = a1[r];
        }
        __syncthreads();                                     // sync2

        // elementwise: thread (b, jj) handles j = 2jj, 2jj+1
        float ai0 = gbuf[0][b][2 * jj] + bf2f(xc0 & 0xffffu);
        float ai1 = gbuf[0][b][2 * jj + 1] + bf2f(xc0 >> 16);
        float aj0 = gbuf[1][b][2 * jj] + bf2f(xc1 & 0xffffu);
        float aj1 = gbuf[1][b][2 * jj + 1] + bf2f(xc1 >> 16);
        float af0 = gbuf[2][b][2 * jj] + bf2f(xc2 & 0xffffu);
        float af1 = gbuf[2][b][2 * jj + 1] + bf2f(xc2 >> 16);
        float ao0 = gbuf[3][b][2 * jj] + bf2f(xc3 & 0xffffu);
        float ao1 = gbuf[3][b][2 * jj + 1] + bf2f(xc3 >> 16);
        c0 = c0 * sigm(af0 + 1.0f) + sigm(ai0) * tanhfast(aj0);
        c1 = c1 * sigm(af1 + 1.0f) + sigm(ai1) * tanhfast(aj1);
        float h0 = tanhfast(c0) * sigm(ao0);
        float h1 = tanhfast(c1) * sigm(ao1);
        unsigned pk = (unsigned)f2bf(h0) | ((unsigned)f2bf(h1) << 16);
        __hip_atomic_store(
            (unsigned*)(hbuf + (size_t)((t + 1) & 1) * 32768 + (size_t)(bg + b) * 512 + j0 + 2 * jj),
            pk, __ATOMIC_RELAXED, __HIP_MEMORY_SCOPE_AGENT);
        hs0 += h0; hs1 += h1;

        if (t < T_ - 1) {
            __syncthreads();                                 // sync3: drains all h stores
            if (tid == 0)
                __hip_atomic_store(flags + g * 64 + slice, (unsigned)(t + 1),
                                   __ATOMIC_RELAXED, __HIP_MEMORY_SCOPE_AGENT);
        }
    }
    float2 hm2 = make_float2(hs0 * (1.f / 1024.f), hs1 * (1.f / 1024.f));
    *(float2*)&hmean[(size_t)(bg + b) * 512 + j0 + 2 * jj] = hm2;
}

// ---------------------------------------------------------------------------
// Kernel 5: preds = sigmoid(hmean @ W_dense + b_dense), one wave per batch row
// ---------------------------------------------------------------------------
__global__ void dense_out(const float* __restrict__ hmean, const float* __restrict__ Wd,
                          const float* __restrict__ bd, float* __restrict__ out) {
    int bb = blockIdx.x;
    int lane = threadIdx.x;
    float p = 0.f;
    for (int e = lane; e < H_; e += 64) p += hmean[(size_t)bb * H_ + e] * Wd[e];
#pragma unroll
    for (int off = 32; off; off >>= 1) p += __shfl_down(p, off);
    if (lane == 0) out[bb] = 1.f / (1.f + __expf(-(p + bd[0])));
}

// ---------------------------------------------------------------------------
extern "C" void kernel_launch(void* const* d_in, const int* in_sizes, int n_in,
                              void* d_out, int out_size, void* d_ws, size_t ws_size,
                              hipStream_t stream) {
    const float* essays  = (const float*)d_in[0];
    const float* W_lstm  = (const float*)d_in[1];
    const float* b_lstm  = (const float*)d_in[2];
    const float* W_dense = (const float*)d_in[3];
    const float* b_dense = (const float*)d_in[4];
    float* out = (float*)d_out;

    char* ws = (char*)d_ws;
    unsigned short* xp   = (unsigned short*)(ws);                   // 256 MB
    unsigned short* Ab   = (unsigned short*)(ws + 268435456ull);    // 40 MB
    unsigned short* Bt   = (unsigned short*)(ws + 310378496ull);    // 1.25 MB
    unsigned short* WhTg = (unsigned short*)(ws + 311689216ull);    // 2 MB
    unsigned short* hbuf = (unsigned short*)(ws + 313786368ull);    // 128 KB
    float*          hm   = (float*)(ws + 313917440ull);             // 128 KB
    unsigned int*   flg  = (unsigned int*)(ws + 314048512ull);      // 1 KB

    hipLaunchKernelGGL(cvt_essays, dim3(81920), dim3(256), 0, stream, essays, Ab);
    hipLaunchKernelGGL(cvt_misc,   dim3(2560),  dim3(256), 0, stream, W_lstm, Bt, hbuf, flg);
    hipLaunchKernelGGL(cvt_wh,     dim3(4096),  dim3(256), 0, stream, W_lstm, WhTg);
    hipLaunchKernelGGL(gemm_xp,    dim3(8192),  dim3(256), 0, stream, Ab, Bt, b_lstm, xp);
    hipLaunchKernelGGL(lstm_rec,   dim3(64),    dim3(256), 0, stream, WhTg, xp, hbuf, hm, flg);
    hipLaunchKernelGGL(dense_out,  dim3(64),    dim3(64),  0, stream, hm, W_dense, b_dense, out);
}